// Round 1
// baseline (249.329 us; speedup 1.0000x reference)
//
#include <hip/hip_runtime.h>

#define BATCH 16
#define T_LEN 2048
#define E_DIM 768
#define N_SENT 32
#define S_LEN 64
#define TSPLIT 16
#define TCHUNK (T_LEN / TSPLIT)   // 128

// -------- Kernel 1: partial column sums over T (deterministic, no atomics) --------
// grid (BATCH, E_DIM/256, TSPLIT), block 256
// partial[tc][b][e] = sum_{t in chunk tc} inputs[b, t, e]
__global__ void pool_partial(const float* __restrict__ in, float* __restrict__ partial) {
    const int b  = blockIdx.x;
    const int e  = blockIdx.y * 256 + threadIdx.x;
    const int tc = blockIdx.z;
    const float* p = in + ((size_t)b * T_LEN + (size_t)tc * TCHUNK) * E_DIM + e;
    float s = 0.f;
#pragma unroll 8
    for (int t = 0; t < TCHUNK; ++t) s += p[(size_t)t * E_DIM];
    partial[((size_t)tc * BATCH + b) * E_DIM + e] = s;
}

// -------- Kernel 2: finish mean, tiny matmul, index computation --------
// 1 block, 1024 threads. thread = (b = tid>>6, c = tid&63): one output column of
// offsets = pooled @ W + bias. Wave == one b row -> pooled LDS reads broadcast.
__global__ void compute_idx(const float* __restrict__ partial,
                            const float* __restrict__ W,
                            const float* __restrict__ bias,
                            int* __restrict__ sidx, int* __restrict__ eidx) {
    __shared__ float pooled[BATCH * E_DIM];   // 48 KB
    __shared__ int   offi[BATCH * 2 * N_SENT];
    const int tid = threadIdx.x;

    // reduce TSPLIT partials -> pooled (mean)
    for (int i = tid; i < BATCH * E_DIM; i += 1024) {
        float s = 0.f;
#pragma unroll
        for (int t = 0; t < TSPLIT; ++t) s += partial[(size_t)t * (BATCH * E_DIM) + i];
        pooled[i] = s * (1.0f / (float)T_LEN);
    }
    __syncthreads();

    const int b = tid >> 6;
    const int c = tid & 63;
    float acc = bias[c];
    const float* pb = pooled + b * E_DIM;
#pragma unroll 8
    for (int e = 0; e < E_DIM; ++e) acc += pb[e] * W[e * (2 * N_SENT) + c];
    // clip to [0, 63] then truncate (nonneg -> floor), matching astype(int32)
    float cl = fminf(fmaxf(acc, 0.f), (float)(S_LEN - 1));
    offi[b * 64 + c] = (int)cl;
    __syncthreads();

    if (c < N_SENT) {
        const int so   = offi[b * 64 + c];
        const int eo   = offi[b * 64 + N_SENT + c];
        const int base = c * S_LEN;
        int si = min(base + so, T_LEN - S_LEN);            // clip(base+so, 0, T-L), so>=0
        si = max(si, 0);
        int ei = min(max(base + S_LEN + eo, si), T_LEN);   // clip(base+L+eo, si, T)
        sidx[b * N_SENT + c] = si;
        eidx[b * N_SENT + c] = ei;
    }
}

// -------- Kernel 3: gather rows (or zeros) --------
// block (192, 4): threadIdx.x = float4 index within a 768-float row (192*16B = 3 KB),
// threadIdx.y = row within block. grid = B*S*L/4 blocks. 192 % 64 == 0 so each wave
// stays inside one row -> sidx/eidx loads are wave-uniform scalar loads.
__global__ void gather_rows(const float* __restrict__ in,
                            const int* __restrict__ sidx,
                            const int* __restrict__ eidx,
                            float4* __restrict__ out) {
    const int row = blockIdx.x * 4 + threadIdx.y;   // b*S*L + s*L + j
    const int j = row & (S_LEN - 1);
    const int s = (row >> 6) & (N_SENT - 1);
    const int b = row >> 11;
    const int si = sidx[b * N_SENT + s];
    const int ei = eidx[b * N_SENT + s];
    float4 v = make_float4(0.f, 0.f, 0.f, 0.f);
    if (j < ei - si) {
        int src = si + j;
        src = min(max(src, 0), T_LEN - 1);
        v = *(const float4*)(in + ((size_t)b * T_LEN + src) * E_DIM + threadIdx.x * 4);
    }
    out[(size_t)row * (E_DIM / 4) + threadIdx.x] = v;   // always write (out is poisoned)
}

extern "C" void kernel_launch(void* const* d_in, const int* in_sizes, int n_in,
                              void* d_out, int out_size, void* d_ws, size_t ws_size,
                              hipStream_t stream) {
    const float* in   = (const float*)d_in[0];   // [16, 2048, 768]
    const float* W    = (const float*)d_in[1];   // [768, 64]
    const float* bias = (const float*)d_in[2];   // [64]
    float* out = (float*)d_out;                  // [16, 32, 64, 768]

    float* partial = (float*)d_ws;                                   // 16*16*768 floats
    int*   sidx    = (int*)((char*)d_ws + (size_t)TSPLIT * BATCH * E_DIM * sizeof(float));
    int*   eidx    = sidx + BATCH * N_SENT;

    pool_partial<<<dim3(BATCH, E_DIM / 256, TSPLIT), 256, 0, stream>>>(in, partial);
    compute_idx<<<1, 1024, 0, stream>>>(partial, W, bias, sidx, eidx);
    gather_rows<<<dim3(BATCH * N_SENT * S_LEN / 4), dim3(192, 4), 0, stream>>>(
        in, sidx, eidx, (float4*)out);
}

// Round 2
// 207.051 us; speedup vs baseline: 1.2042x; 1.2042x over previous
//
#include <hip/hip_runtime.h>

#define BATCH 16
#define T_LEN 2048
#define E_DIM 768
#define E4 (E_DIM / 4)        // 192 float4 per row
#define N_SENT 32
#define S_LEN 64
#define NCHUNK 32             // T chunks of 64 rows
#define ROWS_PER_CHUNK (T_LEN / NCHUNK)   // 64

// -------- Kernel 1: partial column sums over T, float4-vectorized --------
// grid (BATCH, NCHUNK), block 192 (3 waves). Each block sums 64 rows of one batch.
__global__ void pool_partial(const float4* __restrict__ in4, float4* __restrict__ partial4) {
    const int tx = threadIdx.x;            // float4 index within row
    const int b  = blockIdx.x;
    const int tc = blockIdx.y;
    const float4* p = in4 + ((size_t)b * T_LEN + (size_t)tc * ROWS_PER_CHUNK) * E4 + tx;
    float4 s = make_float4(0.f, 0.f, 0.f, 0.f);
#pragma unroll 8
    for (int t = 0; t < ROWS_PER_CHUNK; ++t) {
        float4 v = p[(size_t)t * E4];
        s.x += v.x; s.y += v.y; s.z += v.z; s.w += v.w;
    }
    partial4[((size_t)tc * BATCH + b) * E4 + tx] = s;
}

// -------- Kernel 2: finish mean, tiny matmul, index computation --------
// grid BATCH blocks, 256 threads each. Phase 1: reduce NCHUNK partials -> pooled row
// (LDS). Phase 2: offsets = pooled @ W + bias, 64 cols x 4 e-quarters across threads.
// Phase 3: clip/truncate -> start/end indices.
__global__ void compute_idx(const float4* __restrict__ partial4,
                            const float* __restrict__ W,
                            const float* __restrict__ bias,
                            int* __restrict__ sidx, int* __restrict__ eidx) {
    __shared__ float pooled[E_DIM];
    __shared__ float colsum[4][2 * N_SENT];
    __shared__ int   offi[2 * N_SENT];
    const int b   = blockIdx.x;
    const int tid = threadIdx.x;

    if (tid < E4) {
        float4 s = make_float4(0.f, 0.f, 0.f, 0.f);
#pragma unroll
        for (int tc = 0; tc < NCHUNK; ++tc) {
            float4 v = partial4[((size_t)tc * BATCH + b) * E4 + tid];
            s.x += v.x; s.y += v.y; s.z += v.z; s.w += v.w;
        }
        const float inv = 1.0f / (float)T_LEN;
        ((float4*)pooled)[tid] = make_float4(s.x * inv, s.y * inv, s.z * inv, s.w * inv);
    }
    __syncthreads();

    // tid -> (quarter q, column c). Lanes share q -> pooled reads broadcast;
    // consecutive c -> W reads coalesced (W is [768][64] row-major).
    const int c = tid & 63;
    const int q = tid >> 6;
    float acc = 0.f;
    const float* pb = pooled + q * 192;
    const float* Wq = W + (size_t)q * 192 * (2 * N_SENT) + c;
#pragma unroll 8
    for (int e = 0; e < 192; ++e) acc += pb[e] * Wq[(size_t)e * (2 * N_SENT)];
    colsum[q][c] = acc;
    __syncthreads();

    if (tid < 2 * N_SENT) {
        float o = bias[tid] + colsum[0][tid] + colsum[1][tid] + colsum[2][tid] + colsum[3][tid];
        // clip to [0, 63] then truncate (nonneg -> floor), matching astype(int32)
        float cl = fminf(fmaxf(o, 0.f), (float)(S_LEN - 1));
        offi[tid] = (int)cl;
    }
    __syncthreads();

    if (tid < N_SENT) {
        const int so   = offi[tid];
        const int eo   = offi[N_SENT + tid];
        const int base = tid * S_LEN;
        int si = min(base + so, T_LEN - S_LEN);            // clip(base+so, 0, T-L), so>=0
        int ei = min(max(base + S_LEN + eo, si), T_LEN);   // clip(base+L+eo, si, T)
        sidx[b * N_SENT + tid] = si;
        eidx[b * N_SENT + tid] = ei;
    }
}

// -------- Kernel 3: gather rows (or zeros) --------
// block (192, 4): threadIdx.x = float4 index within a 768-float row,
// threadIdx.y = row within block. grid = B*S*L/4 blocks. 192 % 64 == 0 so each wave
// stays inside one row -> sidx/eidx loads are wave-uniform.
__global__ void gather_rows(const float4* __restrict__ in4,
                            const int* __restrict__ sidx,
                            const int* __restrict__ eidx,
                            float4* __restrict__ out4) {
    const int row = blockIdx.x * 4 + threadIdx.y;   // b*S*L + s*L + j
    const int j = row & (S_LEN - 1);
    const int s = (row >> 6) & (N_SENT - 1);
    const int b = row >> 11;
    const int si = sidx[b * N_SENT + s];
    const int ei = eidx[b * N_SENT + s];
    float4 v = make_float4(0.f, 0.f, 0.f, 0.f);
    if (j < ei - si) {
        v = in4[((size_t)b * T_LEN + (si + j)) * E4 + threadIdx.x];
    }
    out4[(size_t)row * E4 + threadIdx.x] = v;   // always write (out is poisoned)
}

extern "C" void kernel_launch(void* const* d_in, const int* in_sizes, int n_in,
                              void* d_out, int out_size, void* d_ws, size_t ws_size,
                              hipStream_t stream) {
    const float4* in4 = (const float4*)d_in[0];  // [16, 2048, 768]
    const float*  W   = (const float*)d_in[1];   // [768, 64]
    const float*  bias= (const float*)d_in[2];   // [64]
    float4* out4 = (float4*)d_out;               // [16, 32, 64, 768]

    float4* partial4 = (float4*)d_ws;            // NCHUNK*BATCH*E4 float4 = 1.5 MB
    int* sidx = (int*)((char*)d_ws + (size_t)NCHUNK * BATCH * E4 * sizeof(float4));
    int* eidx = sidx + BATCH * N_SENT;

    pool_partial<<<dim3(BATCH, NCHUNK), 192, 0, stream>>>(in4, partial4);
    compute_idx<<<BATCH, 256, 0, stream>>>(partial4, W, bias, sidx, eidx);
    gather_rows<<<dim3(BATCH * N_SENT * S_LEN / 4), dim3(192, 4), 0, stream>>>(
        in4, sidx, eidx, (float4*)out4);
}